// Round 9
// baseline (1210.574 us; speedup 1.0000x reference)
//
#include <hip/hip_runtime.h>

#define B_    8
#define C_    256
#define R_    14
#define R2    196
#define N3    2744     // 14^3
#define NP    2752     // padded (43*64): guard-free tile staging
#define NH    4
#define KD    16
#define DV    64
#define QKVO  96       // 2*KD + DV
#define MT    64       // m-tile in attention
#define NTILE 43
#define SPLIT 4
#define TPC   11       // tiles per m-chunk
#define NCNT  (43 * B_)

#define SC2   0.36067376f   // 0.25 * log2(e)
#define LOG2E 1.44269504f

typedef __attribute__((ext_vector_type(8))) short short8v;
typedef __attribute__((ext_vector_type(4))) short short4v;
typedef __attribute__((ext_vector_type(4))) float float4v;

__device__ __forceinline__ int iabs(int v){ return v < 0 ? -v : v; }

// fp32 -> bf16 round-to-nearest-even (finite inputs)
__device__ __forceinline__ short f2bf(float f){
    union { float f; unsigned int u; } c; c.f = f;
    return (short)((c.u + 0x7FFFu + ((c.u >> 16) & 1u)) >> 16);
}
__device__ __forceinline__ float bf2f(short s){
    union { unsigned int u; float f; } c; c.u = ((unsigned int)(unsigned short)s) << 16;
    return c.f;
}

// ---------------------------------------------------------------------------
// Wp -> bf16 hi/lo split (once) + zero the attn completion counters.
// grid 256, block 256.
// ---------------------------------------------------------------------------
__global__ __launch_bounds__(256)
void wprep_kernel(const float* __restrict__ Wp, short* __restrict__ whi,
                  short* __restrict__ wlo, int* __restrict__ cnt)
{
    int i = blockIdx.x * 256 + threadIdx.x;   // 65536 total
    if (i < NCNT) cnt[i] = 0;                 // poison-safe init each launch
    float w = Wp[i];
    short hi = f2bf(w);
    short lo = f2bf(w - bf2f(hi));
    whi[i] = hi; wlo[i] = lo;
}

// ---------------------------------------------------------------------------
// QKV: og 0: q(o 0..15)->fp32 q0; og 1: k(o 16..31)->bf16 kbf[n][16];
//      og 2/3: v(o 32..63 / 64..95)->bf16 vbf[c][NP]
// Pad rows n in [N3, NP) are ZEROED (attn relies on this for guard-free tiles).
// grid (11, B, 4), block 256
// ---------------------------------------------------------------------------
__global__ __launch_bounds__(256)
void qkv_kernel(const float* __restrict__ x, const float* __restrict__ h,
                const float* __restrict__ W, const float* __restrict__ sc,
                const float* __restrict__ bi,
                float* __restrict__ q0, short* __restrict__ kbf, short* __restrict__ vbf,
                int head)
{
    int b = blockIdx.y;
    int og = blockIdx.z;
    int n = blockIdx.x * 256 + threadIdx.x;
    if (n >= N3) {
        if (n < NP) {   // zero the pad rows once per call (deterministic)
            if (og == 0) {
                float* qo = q0 + (size_t)b * KD * NP + n;
#pragma unroll
                for (int d = 0; d < KD; d++) qo[(size_t)d * NP] = 0.f;
            } else if (og == 1) {
                short8v z8 = {0,0,0,0,0,0,0,0};
                short* ko = kbf + (size_t)b * NP * 16 + (size_t)n * 16;
                *(short8v*)ko = z8; *(short8v*)(ko + 8) = z8;
            } else {
                int cb = (og - 2) * 32;
                short* vo = vbf + (size_t)b * DV * NP + n;
#pragma unroll
                for (int cc = 0; cc < 32; cc++) vo[(size_t)(cb + cc) * NP] = 0;
            }
        }
        return;
    }

    float f[64];
    const float* xb = x + ((size_t)b * C_ + head * DV) * N3 + n;
    if (head == 0) {
#pragma unroll
        for (int c = 0; c < 64; c++) f[c] = xb[(size_t)c * N3];
    } else {
        const float* hb = h + ((size_t)b * C_ + (head - 1) * DV) * N3 + n;
#pragma unroll
        for (int c = 0; c < 64; c++) f[c] = xb[(size_t)c * N3] + hb[(size_t)c * N3];
    }

    const float* Wh  = W  + head * QKVO * 64;   // uniform -> s_loads
    const float* sch = sc + head * QKVO;
    const float* bih = bi + head * QKVO;

    if (og == 0) {                 // q -> fp32
        float* qo = q0 + (size_t)b * KD * NP + n;
        for (int d = 0; d < 16; d++) {
            int o = d;
            float acc = 0.f;
#pragma unroll
            for (int c = 0; c < 64; c++) acc += Wh[o * 64 + c] * f[c];
            qo[(size_t)d * NP] = acc * sch[o] + bih[o];
        }
    } else if (og == 1) {          // k -> bf16, n-major [n][16]
        short kr[16];
        for (int d = 0; d < 16; d++) {
            int o = 16 + d;
            float acc = 0.f;
#pragma unroll
            for (int c = 0; c < 64; c++) acc += Wh[o * 64 + c] * f[c];
            kr[d] = f2bf(acc * sch[o] + bih[o]);
        }
        short* ko = kbf + (size_t)b * NP * 16 + (size_t)n * 16;
        short8v s0, s1;
#pragma unroll
        for (int i2 = 0; i2 < 8; i2++) { s0[i2] = kr[i2]; s1[i2] = kr[8 + i2]; }
        *(short8v*)ko = s0;
        *(short8v*)(ko + 8) = s1;
    } else {                       // v -> bf16 [c][NP]
        int cb = (og - 2) * 32;
        short* vo = vbf + (size_t)b * DV * NP + n;
        for (int cc = 0; cc < 32; cc++) {
            int o = 32 + cb + cc;
            float acc = 0.f;
#pragma unroll
            for (int c = 0; c < 64; c++) acc += Wh[o * 64 + c] * f[c];
            vo[(size_t)(cb + cc) * NP] = f2bf(acc * sch[o] + bih[o]);
        }
    }
}

// ---------------------------------------------------------------------------
// Depthwise 5x5x5 SAME conv: zero-padded 18^3 LDS volume, branchless.
// grid (KD, B), block 256
// ---------------------------------------------------------------------------
__global__ __launch_bounds__(256)
void dwconv_kernel(float* __restrict__ q0, const float* __restrict__ Wdw,
                   const float* __restrict__ dsc, const float* __restrict__ dbi,
                   int head)
{
    __shared__ float pv[18 * 18 * 18];
    int b = blockIdx.y, c = blockIdx.x;
    int t = threadIdx.x;
    float* qc = q0 + ((size_t)b * KD + c) * NP;

    for (int i = t; i < 5832; i += 256) pv[i] = 0.f;
    __syncthreads();
    for (int i = t; i < N3; i += 256) {
        int xx = i / R2; int rem = i - xx * R2; int yy = rem / R_; int zz = rem - yy * R_;
        pv[(xx + 2) * 324 + (yy + 2) * 18 + (zz + 2)] = qc[i];
    }
    __syncthreads();

    const float* w = Wdw + (head * KD + c) * 125;
    float scl = dsc[head * KD + c], bia = dbi[head * KD + c];

    if (t < R2) {
        int x = t / R_, y = t - (t / R_) * R_;
        float acc[14];
#pragma unroll
        for (int z = 0; z < 14; z++) acc[z] = 0.f;
#pragma unroll
        for (int a = 0; a < 5; a++) {
#pragma unroll
            for (int bb = 0; bb < 5; bb++) {
                const float* base = &pv[(x + a) * 324 + (y + bb) * 18];
                float col[18];
#pragma unroll
                for (int j = 0; j < 18; j++) col[j] = base[j];
#pragma unroll
                for (int cc = 0; cc < 5; cc++) {
                    float wv = w[a * 25 + bb * 5 + cc];
#pragma unroll
                    for (int z = 0; z < 14; z++) acc[z] += wv * col[z + cc];
                }
            }
        }
        float* qo = qc + x * R2 + y * R_;
#pragma unroll
        for (int z = 0; z < 14; z++) qo[z] = acc[z] * scl + bia;
    }
}

// ---------------------------------------------------------------------------
// Attention partial v9: bf16 MFMA + lean softmax + register prefetch (T14)
// + fused combine (last z-block per (bx,b) sums the SPLIT partials -> h).
// grid (43, B, SPLIT), block 256.
// ---------------------------------------------------------------------------
__global__ __launch_bounds__(256, 4)
void attn_partial(const float* __restrict__ q0, const short* __restrict__ kbf,
                  const short* __restrict__ vbf, float* __restrict__ pacc,
                  float* __restrict__ pl, const float* __restrict__ abias,
                  float* __restrict__ h, int* __restrict__ cnt, int head)
{
    __shared__ short ktT[64][40];      // [m][d], d 0..15 real, 16..31 zeros, pad->40
    __shared__ short vtT[64][72];      // [c][m], pad 72
    __shared__ short plds[4][16][72];  // per-wave P [n][m]
    __shared__ int   mxa[64];
    __shared__ float ab2[200];         // bias * log2e; [196..199] = -20000 sentinel
    __shared__ int   lastf;

    const int b = blockIdx.y, z = blockIdx.z;
    const int qbase = blockIdx.x * 64;
    const int t = threadIdx.x;
    const int w = t >> 6;
    const int l = t & 63;
    const int g = l >> 4;
    const int ln = l & 15;

    if (t < 196) ab2[t] = abias[head * R2 + t] * LOG2E;
    else if (t < 200) ab2[t] = -20000.0f;

    const float* qq  = q0  + (size_t)b * KD * NP;
    const short* kbs = kbf + (size_t)b * NP * 16;
    const short* vbs = vbf + (size_t)b * DV * NP;

    // zero-fill ktT d=16..31 (in-loop staging only writes d<16)
    {
        int mm = t & 63, dg = t >> 6;
        short4v zz = {0, 0, 0, 0};
        *(short4v*)&ktT[mm][16 + dg * 4] = zz;
    }

    const int n_my = qbase + w * 16 + ln;
    short8v qf;
#pragma unroll
    for (int j = 0; j < 8; j++) {
        int d = g * 8 + j;
        qf[j] = (d < KD) ? f2bf(qq[(size_t)d * NP + n_my]) : (short)0;
    }
    const int nmc = n_my < N3 ? n_my : 0;
    const int nx = nmc / R2, ny = (nmc - nx * R2) / R_;

    float4v acc[4];
#pragma unroll
    for (int cs = 0; cs < 4; cs++) acc[cs] = (float4v){0.f, 0.f, 0.f, 0.f};
    float lsum = 0.f;

    // prefetch registers (staging thread split: row smm, quarter sq)
    const int smm = t >> 2, sq = t & 3;
    short4v kpre;
    short8v vpre0, vpre1;
    {
        const int m0 = (z * TPC) * MT;
        kpre = *(const short4v*)(kbs + (size_t)(m0 + smm) * 16 + sq * 4);
        const short* vs = vbs + (size_t)smm * NP + m0 + sq * 16;
        vpre0 = ((const short8v*)vs)[0];
        vpre1 = ((const short8v*)vs)[1];
    }

    const int tEnd = min(z * TPC + TPC, NTILE);
    for (int t0 = z * TPC; t0 < tEnd; t0++) {
        const int m0 = t0 * MT;
        __syncthreads();                       // prev tile's LDS reads done
        *(short4v*)&ktT[smm][sq * 4]      = kpre;
        *(short8v*)&vtT[smm][sq * 16]     = vpre0;
        *(short8v*)&vtT[smm][sq * 16 + 8] = vpre1;
        if (t < 64) {
            int m = m0 + t;
            int mx, my;
            if (m < N3) { mx = m / R2; int rem = m - mx * R2; my = rem / R_; }
            else        { mx = 220; my = 220; }   // sentinel -> idx >= 196 -> clamp
            mxa[t] = (mx << 8) | my;
        }
        if (t0 + 1 < tEnd) {                   // prefetch next tile (in flight
            const int m1 = (t0 + 1) * MT;      //  across the compute phase)
            kpre = *(const short4v*)(kbs + (size_t)(m1 + smm) * 16 + sq * 4);
            const short* vs = vbs + (size_t)smm * NP + m1 + sq * 16;
            vpre0 = ((const short8v*)vs)[0];
            vpre1 = ((const short8v*)vs)[1];
        }
        __syncthreads();                       // tile staged

        // ---- QK^T + softmax (guard-free) ----
#pragma unroll
        for (int ms = 0; ms < 4; ms++) {
            short8v af = *(const short8v*)&ktT[ms * 16 + ln][g * 8];
            float4v zf = {0.f, 0.f, 0.f, 0.f};
            float4v s = __builtin_amdgcn_mfma_f32_16x16x32_bf16(af, qf, zf, 0, 0, 0);
            int4 pk4 = *(const int4*)&mxa[ms * 16 + g * 4];
            int pka[4] = {pk4.x, pk4.y, pk4.z, pk4.w};
            float p[4];
#pragma unroll
            for (int r = 0; r < 4; r++) {
                int mx = pka[r] >> 8, my = pka[r] & 255;
                int dx, idx;
                asm("v_sad_u32 %0, %1, %2, 0" : "=v"(dx) : "v"(nx), "v"(mx));
                int t14 = dx * 14;
                asm("v_sad_u32 %0, %1, %2, %3" : "=v"(idx) : "v"(ny), "v"(my), "v"(t14));
                idx = idx < 196 ? idx : 196;
                float lg2 = fmaf(s[r], SC2, ab2[idx]);
                p[r] = exp2f(lg2);
                lsum += p[r];
            }
            unsigned pk01, pk23;
            asm("v_cvt_pk_bf16_f32 %0, %1, %2" : "=v"(pk01) : "v"(p[0]), "v"(p[1]));
            asm("v_cvt_pk_bf16_f32 %0, %1, %2" : "=v"(pk23) : "v"(p[2]), "v"(p[3]));
            uint2 pw = make_uint2(pk01, pk23);
            *(uint2*)&plds[w][ln][ms * 16 + g * 4] = pw;
        }

        // ---- PV ----
#pragma unroll
        for (int ck = 0; ck < 2; ck++) {
            short8v pa = *(const short8v*)&plds[w][ln][ck * 32 + g * 8];
#pragma unroll
            for (int cs = 0; cs < 4; cs++) {
                short8v vf = *(const short8v*)&vtT[cs * 16 + ln][ck * 32 + g * 8];
                acc[cs] = __builtin_amdgcn_mfma_f32_16x16x32_bf16(pa, vf, acc[cs], 0, 0, 0);
            }
        }
    }

    // ---- epilogue: publish partials ----
    lsum += __shfl_xor(lsum, 16);
    lsum += __shfl_xor(lsum, 32);

    float* pbase = pacc + (size_t)(b * SPLIT + z) * DV * NP;
    if (l < 16) {
        int n_l = qbase + w * 16 + l;
        if (n_l < N3) pl[(size_t)(b * SPLIT + z) * NP + n_l] = lsum;
    }
    const int n0w = qbase + w * 16 + g * 4;
    if (n0w < N3) {
#pragma unroll
        for (int cs = 0; cs < 4; cs++) {
            int c = cs * 16 + ln;
            *(float4v*)&pbase[(size_t)c * NP + n0w] = acc[cs];
        }
    }

    // ---- fused combine: last z-block for this (bx,b) reduces to h ----
    __threadfence();                         // release partials (all threads)
    __syncthreads();
    if (t == 0) lastf = atomicAdd(&cnt[b * 43 + blockIdx.x], 1);
    __syncthreads();
    if (lastf == SPLIT - 1) {
        __threadfence();                     // acquire other blocks' partials
        int nl = t & 63;
        int n = qbase + nl;
        int cg = t >> 6;
        if (n < N3) {
            float ltot = 0.f;
#pragma unroll
            for (int zz = 0; zz < SPLIT; zz++)
                ltot += pl[(size_t)(b * SPLIT + zz) * NP + n];
            float inv = 1.f / ltot;
            const float* pb = pacc + (size_t)b * SPLIT * DV * NP + n;
            float* hb = h + ((size_t)b * C_ + head * DV) * N3 + n;
#pragma unroll
            for (int cc = 0; cc < 16; cc++) {
                int c = cg * 16 + cc;
                float a = 0.f;
#pragma unroll
                for (int zz = 0; zz < SPLIT; zz++)
                    a += pb[(size_t)(zz * DV + c) * NP];
                hb[(size_t)c * N3] = a * inv;
            }
        }
        if (t == 0) atomicExch(&cnt[b * 43 + blockIdx.x], 0);   // reset for next head
    }
}

// ---------------------------------------------------------------------------
// Projection: split-bf16 MFMA. out = psc*(Wp @ relu(h)) + pbi
// grid (43 n-tiles, B), block 256
// ---------------------------------------------------------------------------
__global__ __launch_bounds__(256, 2)
void proj_kernel(const float* __restrict__ h, const short* __restrict__ whi,
                 const short* __restrict__ wlo, const float* __restrict__ psc,
                 const float* __restrict__ pbi, float* __restrict__ out)
{
    __shared__ short hhi[64][40];
    __shared__ short hlo[64][40];

    const int b = blockIdx.y;
    const int n0 = blockIdx.x * 64;
    const int t = threadIdx.x;
    const int w = t >> 6, l = t & 63, g = l >> 4, ln = l & 15;

    float4v acc[4][4];
#pragma unroll
    for (int os = 0; os < 4; os++)
#pragma unroll
        for (int ns = 0; ns < 4; ns++) acc[os][ns] = (float4v){0.f, 0.f, 0.f, 0.f};

    const float* hb = h + (size_t)b * C_ * N3;
    const int sc = t >> 3;
    const int sn = (t & 7) * 8;

    for (int c0 = 0; c0 < 256; c0 += 32) {
        __syncthreads();
        {
            const float* hsrc = hb + (size_t)(c0 + sc) * N3 + n0 + sn;
            float4 f0 = ((const float4*)hsrc)[0];
            float4 f1 = ((const float4*)hsrc)[1];
            float va[8] = { f0.x, f0.y, f0.z, f0.w, f1.x, f1.y, f1.z, f1.w };
#pragma unroll
            for (int u = 0; u < 8; u++) {
                float v = va[u] > 0.f ? va[u] : 0.f;
                short hi = f2bf(v);
                short lo = f2bf(v - bf2f(hi));
                hhi[sn + u][sc] = hi;
                hlo[sn + u][sc] = lo;
            }
        }
        __syncthreads();

        short8v wh[4], wl[4];
#pragma unroll
        for (int os = 0; os < 4; os++) {
            size_t off = (size_t)(64 * w + os * 16 + ln) * 256 + c0 + g * 8;
            wh[os] = *(const short8v*)(whi + off);
            wl[os] = *(const short8v*)(wlo + off);
        }
#pragma unroll
        for (int ns = 0; ns < 4; ns++) {
            short8v bh = *(const short8v*)&hhi[ns * 16 + ln][g * 8];
            short8v bl = *(const short8v*)&hlo[ns * 16 + ln][g * 8];
#pragma unroll
            for (int os = 0; os < 4; os++) {
                acc[os][ns] = __builtin_amdgcn_mfma_f32_16x16x32_bf16(wh[os], bh, acc[os][ns], 0, 0, 0);
                acc[os][ns] = __builtin_amdgcn_mfma_f32_16x16x32_bf16(wh[os], bl, acc[os][ns], 0, 0, 0);
                acc[os][ns] = __builtin_amdgcn_mfma_f32_16x16x32_bf16(wl[os], bh, acc[os][ns], 0, 0, 0);
            }
        }
    }

    float* ob = out + (size_t)b * C_ * N3;
#pragma unroll
    for (int os = 0; os < 4; os++) {
#pragma unroll
        for (int r = 0; r < 4; r++) {
            int o = 64 * w + os * 16 + g * 4 + r;
            float s0 = psc[o], b0 = pbi[o];
#pragma unroll
            for (int ns = 0; ns < 4; ns++) {
                int n = n0 + ns * 16 + ln;
                if (n < N3) ob[(size_t)o * N3 + n] = acc[os][ns][r] * s0 + b0;
            }
        }
    }
}

// ---------------------------------------------------------------------------
extern "C" void kernel_launch(void* const* d_in, const int* in_sizes, int n_in,
                              void* d_out, int out_size, void* d_ws, size_t ws_size,
                              hipStream_t stream)
{
    const float* x    = (const float*)d_in[0];
    const float* Wqkv = (const float*)d_in[1];
    const float* qsc  = (const float*)d_in[2];
    const float* qbi  = (const float*)d_in[3];
    const float* Wdw  = (const float*)d_in[4];
    const float* dsc  = (const float*)d_in[5];
    const float* dbi  = (const float*)d_in[6];
    const float* Wp   = (const float*)d_in[7];
    const float* psc  = (const float*)d_in[8];
    const float* pbi  = (const float*)d_in[9];
    const float* ab   = (const float*)d_in[10];
    // d_in[11] = bias_idx: unused (computed analytically)

    float* out = (float*)d_out;
    char*  wsb = (char*)d_ws;
    float* q0   = (float*)wsb;                                  // B*KD*NP f32
    short* kbf  = (short*)(q0 + (size_t)B_ * KD * NP);          // B*NP*16 bf16
    short* vbf  = kbf + (size_t)B_ * NP * 16;                   // B*DV*NP bf16
    float* h    = (float*)(vbf + (size_t)B_ * DV * NP);         // B*C*N3 f32
    float* pacc = h + (size_t)B_ * C_ * N3;                     // B*SPLIT*DV*NP f32
    float* pl   = pacc + (size_t)B_ * SPLIT * DV * NP;          // B*SPLIT*NP f32
    short* whi  = (short*)(pl + (size_t)B_ * SPLIT * NP);       // 256*256 bf16
    short* wlo  = whi + 256 * 256;                              // 256*256 bf16
    int*   cnt  = (int*)(wlo + 256 * 256);                      // 344 ints

    wprep_kernel<<<256, 256, 0, stream>>>(Wp, whi, wlo, cnt);

    for (int head = 0; head < NH; head++) {
        qkv_kernel<<<dim3(11, B_, 4), 256, 0, stream>>>(x, h, Wqkv, qsc, qbi, q0, kbf, vbf, head);
        dwconv_kernel<<<dim3(KD, B_), 256, 0, stream>>>(q0, Wdw, dsc, dbi, head);
        attn_partial<<<dim3(43, B_, SPLIT), 256, 0, stream>>>(q0, kbf, vbf, pacc, pl, ab, h, cnt, head);
    }
    proj_kernel<<<dim3(43, B_), 256, 0, stream>>>(h, whi, wlo, psc, pbi, out);
}

// Round 10
// 338.046 us; speedup vs baseline: 3.5811x; 3.5811x over previous
//
#include <hip/hip_runtime.h>

#define B_    8
#define C_    256
#define R_    14
#define R2    196
#define N3    2744     // 14^3
#define NP    2752     // padded (43*64): guard-free tile staging
#define NH    4
#define KD    16
#define DV    64
#define QKVO  96       // 2*KD + DV
#define MT    64       // m-tile in attention
#define NTILE 43
#define SPLIT 4
#define TPC   11       // tiles per m-chunk

#define SC2   0.36067376f   // 0.25 * log2(e)
#define LOG2E 1.44269504f

typedef __attribute__((ext_vector_type(8))) short short8v;
typedef __attribute__((ext_vector_type(4))) short short4v;
typedef __attribute__((ext_vector_type(4))) float float4v;

__device__ __forceinline__ int iabs(int v){ return v < 0 ? -v : v; }

// fp32 -> bf16 round-to-nearest-even (finite inputs)
__device__ __forceinline__ short f2bf(float f){
    union { float f; unsigned int u; } c; c.f = f;
    return (short)((c.u + 0x7FFFu + ((c.u >> 16) & 1u)) >> 16);
}
__device__ __forceinline__ float bf2f(short s){
    union { unsigned int u; float f; } c; c.u = ((unsigned int)(unsigned short)s) << 16;
    return c.f;
}

// ---------------------------------------------------------------------------
// wprep: Wp -> bf16 hi/lo split; Wqkv*qkv_scale -> bf16 hi/lo split.
// grid 256, block 256 (i < 65536)
// ---------------------------------------------------------------------------
__global__ __launch_bounds__(256)
void wprep_kernel(const float* __restrict__ Wp, short* __restrict__ whi,
                  short* __restrict__ wlo, const float* __restrict__ Wqkv,
                  const float* __restrict__ qsc, short* __restrict__ wqhi,
                  short* __restrict__ wqlo)
{
    int i = blockIdx.x * 256 + threadIdx.x;   // 65536 total
    {
        float w = Wp[i];
        short hi = f2bf(w);
        short lo = f2bf(w - bf2f(hi));
        whi[i] = hi; wlo[i] = lo;
    }
    if (i < NH * QKVO * 64) {                 // 24576
        int o_all = i >> 6;                   // head*96 + o
        float w = Wqkv[i] * qsc[o_all];       // fold scale into W rows
        short hi = f2bf(w);
        short lo = f2bf(w - bf2f(hi));
        wqhi[i] = hi; wqlo[i] = lo;
    }
}

// ---------------------------------------------------------------------------
// QKV v10: split-bf16 MFMA GEMM. y[96][64n] = Wq'[96][64] @ feat[64][64n] + bi
// feat = x_chunk (+ prev h). Writes q fp32 (q0), k bf16 [n][16], v bf16 [c][NP];
// pad n in [N3,NP) written as ZERO (attn relies on this).
// grid (43, B), block 256 (4 waves; wave w -> n-subtile w)
// ---------------------------------------------------------------------------
__global__ __launch_bounds__(256, 2)
void qkv_mfma(const float* __restrict__ x, const float* __restrict__ h,
              const short* __restrict__ wqhi, const short* __restrict__ wqlo,
              const float* __restrict__ qbi,
              float* __restrict__ q0, short* __restrict__ kbf, short* __restrict__ vbf,
              int head)
{
    __shared__ short fhi[64][72];   // [n][c] feat hi
    __shared__ short flo[64][72];   // [n][c] feat lo
    __shared__ float bsh[96];

    const int b = blockIdx.y;
    const int n0 = blockIdx.x * 64;
    const int t = threadIdx.x;
    const int w = t >> 6, l = t & 63, g = l >> 4, ln = l & 15;

    if (t < 96) bsh[t] = qbi[head * QKVO + t];

    // ---- stage feat transposed, hi/lo split: thread = (c = t&63, n-group) ----
    {
        const int sc_ = t & 63;
        const int sng = (t >> 6) * 16;        // n local base
        const float* xs = x + ((size_t)b * C_ + head * DV + sc_) * N3 + n0 + sng;
        const float* hs = h + ((size_t)b * C_ + (head - 1) * DV + sc_) * N3 + n0 + sng;
        float fv[16];
        if (n0 + sng + 15 < N3) {
#pragma unroll
            for (int e4 = 0; e4 < 4; e4++) {
                float4 xv = ((const float4*)xs)[e4];
                fv[4*e4+0] = xv.x; fv[4*e4+1] = xv.y; fv[4*e4+2] = xv.z; fv[4*e4+3] = xv.w;
            }
            if (head > 0) {
#pragma unroll
                for (int e4 = 0; e4 < 4; e4++) {
                    float4 hv = ((const float4*)hs)[e4];
                    fv[4*e4+0] += hv.x; fv[4*e4+1] += hv.y; fv[4*e4+2] += hv.z; fv[4*e4+3] += hv.w;
                }
            }
        } else {
#pragma unroll
            for (int e = 0; e < 16; e++) {
                int n = n0 + sng + e;
                float v = (n < N3) ? xs[e] : 0.f;
                if (head > 0 && n < N3) v += hs[e];
                fv[e] = v;
            }
        }
#pragma unroll
        for (int e = 0; e < 16; e++) {
            short hi = f2bf(fv[e]);
            short lo = f2bf(fv[e] - bf2f(hi));
            fhi[sng + e][sc_] = hi;
            flo[sng + e][sc_] = lo;
        }
    }
    __syncthreads();

    // ---- GEMM: 6 o-subtiles x this wave's n-subtile, K=64 ----
    float4v acc[6];
#pragma unroll
    for (int os = 0; os < 6; os++) acc[os] = (float4v){0.f, 0.f, 0.f, 0.f};

    const short* wqh = wqhi + head * QKVO * 64;
    const short* wql = wqlo + head * QKVO * 64;
#pragma unroll
    for (int ck = 0; ck < 2; ck++) {
        short8v bh = *(const short8v*)&fhi[w * 16 + ln][ck * 32 + g * 8];
        short8v bl = *(const short8v*)&flo[w * 16 + ln][ck * 32 + g * 8];
#pragma unroll
        for (int os = 0; os < 6; os++) {
            size_t off = (size_t)(os * 16 + ln) * 64 + ck * 32 + g * 8;
            short8v wh = *(const short8v*)(wqh + off);
            short8v wl = *(const short8v*)(wql + off);
            acc[os] = __builtin_amdgcn_mfma_f32_16x16x32_bf16(wh, bh, acc[os], 0, 0, 0);
            acc[os] = __builtin_amdgcn_mfma_f32_16x16x32_bf16(wh, bl, acc[os], 0, 0, 0);
            acc[os] = __builtin_amdgcn_mfma_f32_16x16x32_bf16(wl, bh, acc[os], 0, 0, 0);
        }
    }

    // ---- epilogue: D[o = os*16+g*4+r][n = n0+w*16+ln] ----
    const int n_ = n0 + w * 16 + ln;          // < NP always
    const bool ok = n_ < N3;
    float* qo = q0 + (size_t)b * KD * NP;
    short* ko = kbf + (size_t)b * NP * 16 + (size_t)n_ * 16;
    short* vo = vbf + (size_t)b * DV * NP;
#pragma unroll
    for (int os = 0; os < 6; os++) {
#pragma unroll
        for (int r = 0; r < 4; r++) {
            int o = os * 16 + g * 4 + r;
            float y = ok ? acc[os][r] + bsh[o] : 0.f;
            if (o < KD)            qo[(size_t)o * NP + n_] = y;
            else if (o < 2 * KD)   ko[o - KD] = f2bf(y);
            else                   vo[(size_t)(o - 2 * KD) * NP + n_] = f2bf(y);
        }
    }
}

// ---------------------------------------------------------------------------
// Depthwise 5x5x5 SAME conv: zero-padded 18^3 LDS volume, branchless.
// grid (KD, B), block 256
// ---------------------------------------------------------------------------
__global__ __launch_bounds__(256)
void dwconv_kernel(float* __restrict__ q0, const float* __restrict__ Wdw,
                   const float* __restrict__ dsc, const float* __restrict__ dbi,
                   int head)
{
    __shared__ float pv[18 * 18 * 18];
    int b = blockIdx.y, c = blockIdx.x;
    int t = threadIdx.x;
    float* qc = q0 + ((size_t)b * KD + c) * NP;

    for (int i = t; i < 5832; i += 256) pv[i] = 0.f;
    __syncthreads();
    for (int i = t; i < N3; i += 256) {
        int xx = i / R2; int rem = i - xx * R2; int yy = rem / R_; int zz = rem - yy * R_;
        pv[(xx + 2) * 324 + (yy + 2) * 18 + (zz + 2)] = qc[i];
    }
    __syncthreads();

    const float* w = Wdw + (head * KD + c) * 125;
    float scl = dsc[head * KD + c], bia = dbi[head * KD + c];

    if (t < R2) {
        int x = t / R_, y = t - (t / R_) * R_;
        float acc[14];
#pragma unroll
        for (int z = 0; z < 14; z++) acc[z] = 0.f;
#pragma unroll
        for (int a = 0; a < 5; a++) {
#pragma unroll
            for (int bb = 0; bb < 5; bb++) {
                const float* base = &pv[(x + a) * 324 + (y + bb) * 18];
                float col[18];
#pragma unroll
                for (int j = 0; j < 18; j++) col[j] = base[j];
#pragma unroll
                for (int cc = 0; cc < 5; cc++) {
                    float wv = w[a * 25 + bb * 5 + cc];
#pragma unroll
                    for (int z = 0; z < 14; z++) acc[z] += wv * col[z + cc];
                }
            }
        }
        float* qo = qc + x * R2 + y * R_;
#pragma unroll
        for (int z = 0; z < 14; z++) qo[z] = acc[z] * scl + bia;
    }
}

// ---------------------------------------------------------------------------
// Attention partial (round-8 proven version): bf16 MFMA + lean softmax.
// grid (43, B, SPLIT), block 256.
// ---------------------------------------------------------------------------
__global__ __launch_bounds__(256, 4)
void attn_partial(const float* __restrict__ q0, const short* __restrict__ kbf,
                  const short* __restrict__ vbf, float* __restrict__ pacc,
                  float* __restrict__ pl, const float* __restrict__ abias, int head)
{
    __shared__ short ktT[64][40];      // [m][d], d 0..15 real, 16..31 zeros, pad->40
    __shared__ short vtT[64][72];      // [c][m], pad 72
    __shared__ short plds[4][16][72];  // per-wave P [n][m]
    __shared__ int   mxa[64];
    __shared__ float ab2[200];         // bias * log2e; [196..199] = -20000 sentinel

    const int b = blockIdx.y, z = blockIdx.z;
    const int qbase = blockIdx.x * 64;
    const int t = threadIdx.x;
    const int w = t >> 6;
    const int l = t & 63;
    const int g = l >> 4;
    const int ln = l & 15;

    if (t < 196) ab2[t] = abias[head * R2 + t] * LOG2E;
    else if (t < 200) ab2[t] = -20000.0f;

    const float* qq  = q0  + (size_t)b * KD * NP;
    const short* kbs = kbf + (size_t)b * NP * 16;
    const short* vbs = vbf + (size_t)b * DV * NP;

    // zero-fill ktT d=16..31 (in-loop staging only writes d<16)
    {
        int mm = t & 63, dg = t >> 6;
        short4v zz = {0, 0, 0, 0};
        *(short4v*)&ktT[mm][16 + dg * 4] = zz;
    }

    const int n_my = qbase + w * 16 + ln;
    short8v qf;
#pragma unroll
    for (int j = 0; j < 8; j++) {
        int d = g * 8 + j;
        qf[j] = (d < KD) ? f2bf(qq[(size_t)d * NP + n_my]) : (short)0;
    }
    const int nmc = n_my < N3 ? n_my : 0;
    const int nx = nmc / R2, ny = (nmc - nx * R2) / R_;

    float4v acc[4];
#pragma unroll
    for (int cs = 0; cs < 4; cs++) acc[cs] = (float4v){0.f, 0.f, 0.f, 0.f};
    float lsum = 0.f;

    const int tEnd = min(z * TPC + TPC, NTILE);
    for (int t0 = z * TPC; t0 < tEnd; t0++) {
        const int m0 = t0 * MT;
        __syncthreads();
        {   // stage K: thread (mm=t>>2, kq=t&3): b64 copy (pad rows are zeros)
            int mm = t >> 2, kq = t & 3;
            short4v kv = *(const short4v*)(kbs + (size_t)(m0 + mm) * 16 + kq * 4);
            *(short4v*)&ktT[mm][kq * 4] = kv;
        }
        {   // stage V: thread (c=t>>2, mq=t&3): 32B copy
            int c = t >> 2, mq = t & 3;
            const short* vs = vbs + (size_t)c * NP + m0 + mq * 16;
            short8v s0 = ((const short8v*)vs)[0];
            short8v s1 = ((const short8v*)vs)[1];
            *(short8v*)&vtT[c][mq * 16]     = s0;
            *(short8v*)&vtT[c][mq * 16 + 8] = s1;
        }
        if (t < 64) {
            int m = m0 + t;
            int mx, my;
            if (m < N3) { mx = m / R2; int rem = m - mx * R2; my = rem / R_; }
            else        { mx = 220; my = 220; }   // sentinel -> idx >= 196 -> clamp
            mxa[t] = (mx << 8) | my;
        }
        __syncthreads();

        // ---- QK^T + softmax (guard-free) ----
#pragma unroll
        for (int ms = 0; ms < 4; ms++) {
            short8v af = *(const short8v*)&ktT[ms * 16 + ln][g * 8];
            float4v zf = {0.f, 0.f, 0.f, 0.f};
            float4v s = __builtin_amdgcn_mfma_f32_16x16x32_bf16(af, qf, zf, 0, 0, 0);
            int4 pk4 = *(const int4*)&mxa[ms * 16 + g * 4];
            int pka[4] = {pk4.x, pk4.y, pk4.z, pk4.w};
            float p[4];
#pragma unroll
            for (int r = 0; r < 4; r++) {
                int mx = pka[r] >> 8, my = pka[r] & 255;
                int dx, idx;
                asm("v_sad_u32 %0, %1, %2, 0" : "=v"(dx) : "v"(nx), "v"(mx));
                int t14 = dx * 14;
                asm("v_sad_u32 %0, %1, %2, %3" : "=v"(idx) : "v"(ny), "v"(my), "v"(t14));
                idx = idx < 196 ? idx : 196;
                float lg2 = fmaf(s[r], SC2, ab2[idx]);
                p[r] = exp2f(lg2);
                lsum += p[r];
            }
            unsigned pk01, pk23;
            asm("v_cvt_pk_bf16_f32 %0, %1, %2" : "=v"(pk01) : "v"(p[0]), "v"(p[1]));
            asm("v_cvt_pk_bf16_f32 %0, %1, %2" : "=v"(pk23) : "v"(p[2]), "v"(p[3]));
            uint2 pw = make_uint2(pk01, pk23);
            *(uint2*)&plds[w][ln][ms * 16 + g * 4] = pw;
        }

        // ---- PV ----
#pragma unroll
        for (int ck = 0; ck < 2; ck++) {
            short8v pa = *(const short8v*)&plds[w][ln][ck * 32 + g * 8];
#pragma unroll
            for (int cs = 0; cs < 4; cs++) {
                short8v vf = *(const short8v*)&vtT[cs * 16 + ln][ck * 32 + g * 8];
                acc[cs] = __builtin_amdgcn_mfma_f32_16x16x32_bf16(pa, vf, acc[cs], 0, 0, 0);
            }
        }
    }

    // ---- epilogue ----
    lsum += __shfl_xor(lsum, 16);
    lsum += __shfl_xor(lsum, 32);

    float* pbase = pacc + (size_t)(b * SPLIT + z) * DV * NP;
    if (l < 16) {
        int n_l = qbase + w * 16 + l;
        if (n_l < N3) pl[(size_t)(b * SPLIT + z) * NP + n_l] = lsum;
    }
    const int n0w = qbase + w * 16 + g * 4;
    if (n0w < N3) {
#pragma unroll
        for (int cs = 0; cs < 4; cs++) {
            int c = cs * 16 + ln;
            *(float4v*)&pbase[(size_t)c * NP + n0w] = acc[cs];
        }
    }
}

// ---------------------------------------------------------------------------
// Combine SPLIT partials: h = (sum_z acc_z) / (sum_z l_z)
// grid (11, B, 4 ch-groups), block 256
// ---------------------------------------------------------------------------
__global__ __launch_bounds__(256)
void attn_combine(const float* __restrict__ pacc, const float* __restrict__ pl,
                  float* __restrict__ h, int head)
{
    int b = blockIdx.y;
    int ch0 = blockIdx.z * 16;
    int r = blockIdx.x * 256 + threadIdx.x;
    if (r >= N3) return;
    float l = 0.f;
#pragma unroll
    for (int z = 0; z < SPLIT; z++) l += pl[(size_t)(b * SPLIT + z) * NP + r];
    float inv = 1.f / l;
    float* hb = h + ((size_t)b * C_ + head * DV) * N3 + r;
    const float* pb = pacc + (size_t)b * SPLIT * DV * NP + r;
#pragma unroll
    for (int cc = 0; cc < 16; cc++) {
        int ch = ch0 + cc;
        float a = 0.f;
#pragma unroll
        for (int z = 0; z < SPLIT; z++) a += pb[(size_t)(z * DV + ch) * NP];
        hb[(size_t)ch * N3] = a * inv;
    }
}

// ---------------------------------------------------------------------------
// Projection: split-bf16 MFMA. out = psc*(Wp @ relu(h)) + pbi
// grid (43 n-tiles, B), block 256
// ---------------------------------------------------------------------------
__global__ __launch_bounds__(256, 2)
void proj_kernel(const float* __restrict__ h, const short* __restrict__ whi,
                 const short* __restrict__ wlo, const float* __restrict__ psc,
                 const float* __restrict__ pbi, float* __restrict__ out)
{
    __shared__ short hhi[64][40];
    __shared__ short hlo[64][40];

    const int b = blockIdx.y;
    const int n0 = blockIdx.x * 64;
    const int t = threadIdx.x;
    const int w = t >> 6, l = t & 63, g = l >> 4, ln = l & 15;

    float4v acc[4][4];
#pragma unroll
    for (int os = 0; os < 4; os++)
#pragma unroll
        for (int ns = 0; ns < 4; ns++) acc[os][ns] = (float4v){0.f, 0.f, 0.f, 0.f};

    const float* hb = h + (size_t)b * C_ * N3;
    const int sc = t >> 3;
    const int sn = (t & 7) * 8;

    for (int c0 = 0; c0 < 256; c0 += 32) {
        __syncthreads();
        {
            const float* hsrc = hb + (size_t)(c0 + sc) * N3 + n0 + sn;
            float4 f0 = ((const float4*)hsrc)[0];
            float4 f1 = ((const float4*)hsrc)[1];
            float va[8] = { f0.x, f0.y, f0.z, f0.w, f1.x, f1.y, f1.z, f1.w };
#pragma unroll
            for (int u = 0; u < 8; u++) {
                float v = va[u] > 0.f ? va[u] : 0.f;
                short hi = f2bf(v);
                short lo = f2bf(v - bf2f(hi));
                hhi[sn + u][sc] = hi;
                hlo[sn + u][sc] = lo;
            }
        }
        __syncthreads();

        short8v wh[4], wl[4];
#pragma unroll
        for (int os = 0; os < 4; os++) {
            size_t off = (size_t)(64 * w + os * 16 + ln) * 256 + c0 + g * 8;
            wh[os] = *(const short8v*)(whi + off);
            wl[os] = *(const short8v*)(wlo + off);
        }
#pragma unroll
        for (int ns = 0; ns < 4; ns++) {
            short8v bh = *(const short8v*)&hhi[ns * 16 + ln][g * 8];
            short8v bl = *(const short8v*)&hlo[ns * 16 + ln][g * 8];
#pragma unroll
            for (int os = 0; os < 4; os++) {
                acc[os][ns] = __builtin_amdgcn_mfma_f32_16x16x32_bf16(wh[os], bh, acc[os][ns], 0, 0, 0);
                acc[os][ns] = __builtin_amdgcn_mfma_f32_16x16x32_bf16(wh[os], bl, acc[os][ns], 0, 0, 0);
                acc[os][ns] = __builtin_amdgcn_mfma_f32_16x16x32_bf16(wl[os], bh, acc[os][ns], 0, 0, 0);
            }
        }
    }

    float* ob = out + (size_t)b * C_ * N3;
#pragma unroll
    for (int os = 0; os < 4; os++) {
#pragma unroll
        for (int r = 0; r < 4; r++) {
            int o = 64 * w + os * 16 + g * 4 + r;
            float s0 = psc[o], b0 = pbi[o];
#pragma unroll
            for (int ns = 0; ns < 4; ns++) {
                int n = n0 + ns * 16 + ln;
                if (n < N3) ob[(size_t)o * N3 + n] = acc[os][ns][r] * s0 + b0;
            }
        }
    }
}

// ---------------------------------------------------------------------------
extern "C" void kernel_launch(void* const* d_in, const int* in_sizes, int n_in,
                              void* d_out, int out_size, void* d_ws, size_t ws_size,
                              hipStream_t stream)
{
    const float* x    = (const float*)d_in[0];
    const float* Wqkv = (const float*)d_in[1];
    const float* qsc  = (const float*)d_in[2];
    const float* qbi  = (const float*)d_in[3];
    const float* Wdw  = (const float*)d_in[4];
    const float* dsc  = (const float*)d_in[5];
    const float* dbi  = (const float*)d_in[6];
    const float* Wp   = (const float*)d_in[7];
    const float* psc  = (const float*)d_in[8];
    const float* pbi  = (const float*)d_in[9];
    const float* ab   = (const float*)d_in[10];
    // d_in[11] = bias_idx: unused (computed analytically)

    float* out = (float*)d_out;
    char*  wsb = (char*)d_ws;
    float* q0   = (float*)wsb;                                  // B*KD*NP f32
    short* kbf  = (short*)(q0 + (size_t)B_ * KD * NP);          // B*NP*16 bf16
    short* vbf  = kbf + (size_t)B_ * NP * 16;                   // B*DV*NP bf16
    float* h    = (float*)(vbf + (size_t)B_ * DV * NP);         // B*C*N3 f32
    float* pacc = h + (size_t)B_ * C_ * N3;                     // B*SPLIT*DV*NP f32
    float* pl   = pacc + (size_t)B_ * SPLIT * DV * NP;          // B*SPLIT*NP f32
    short* whi  = (short*)(pl + (size_t)B_ * SPLIT * NP);       // 256*256 bf16
    short* wlo  = whi + 256 * 256;                              // 256*256 bf16
    short* wqhi = wlo + 256 * 256;                              // 4*96*64 bf16
    short* wqlo = wqhi + NH * QKVO * 64;                        // 4*96*64 bf16

    wprep_kernel<<<256, 256, 0, stream>>>(Wp, whi, wlo, Wqkv, qsc, wqhi, wqlo);

    for (int head = 0; head < NH; head++) {
        qkv_mfma<<<dim3(43, B_), 256, 0, stream>>>(x, h, wqhi, wqlo, qbi, q0, kbf, vbf, head);
        dwconv_kernel<<<dim3(KD, B_), 256, 0, stream>>>(q0, Wdw, dsc, dbi, head);
        attn_partial<<<dim3(43, B_, SPLIT), 256, 0, stream>>>(q0, kbf, vbf, pacc, pl, ab, head);
        attn_combine<<<dim3(11, B_, 4), 256, 0, stream>>>(pacc, pl, h, head);
    }
    proj_kernel<<<dim3(43, B_), 256, 0, stream>>>(h, whi, wlo, psc, pbi, out);
}